// Round 14
// baseline (377.293 us; speedup 1.0000x reference)
//
#include <hip/hip_runtime.h>
#include <hip/hip_bf16.h>

#define NN_NODES 20000
#define NE_EDGES 500000
#define KTOT 48

typedef __bf16 bf16x8 __attribute__((ext_vector_type(8)));
typedef float f32x4 __attribute__((ext_vector_type(4)));

__device__ inline unsigned short bf16_rne(float x) {
    unsigned int u = __float_as_uint(x);
    u = (u + 0x7fffu + ((u >> 16) & 1u)) >> 16;
    return (unsigned short)u;
}

// ---------------------------------------------------------------------------
// Zero helper
// ---------------------------------------------------------------------------
__global__ void zero_kernel(int* __restrict__ p, int n) {
    int i = blockIdx.x * 256 + threadIdx.x;
    if (i < n) p[i] = 0;
}

// ---------------------------------------------------------------------------
// CSR build
// ---------------------------------------------------------------------------
__global__ void count_kernel(const int* __restrict__ ei, int* __restrict__ counts) {
    int e = blockIdx.x * 256 + threadIdx.x;
    if (e < NE_EDGES) atomicAdd(&counts[ei[NE_EDGES + e]], 1);
}

__global__ void scan_kernel(const int* __restrict__ counts, int* __restrict__ row_start) {
    __shared__ int part[256];
    const int CH = (NN_NODES + 255) / 256;
    int t = threadIdx.x;
    int begin = t * CH;
    int end = begin + CH;
    if (end > NN_NODES) end = NN_NODES;
    int sum = 0;
    for (int i = begin; i < end && i < NN_NODES; ++i) sum += counts[i];
    part[t] = sum;
    __syncthreads();
    for (int off = 1; off < 256; off <<= 1) {
        int v = (t >= off) ? part[t - off] : 0;
        __syncthreads();
        part[t] += v;
        __syncthreads();
    }
    int run = (t == 0) ? 0 : part[t - 1];
    for (int i = begin; i < end && i < NN_NODES; ++i) {
        row_start[i] = run;
        run += counts[i];
    }
    if (t == 255) row_start[NN_NODES] = part[255];
}

__global__ void fill_kernel(const int* __restrict__ ei, const int* __restrict__ row_start,
                            int* __restrict__ cursor, int* __restrict__ slot_pos) {
    int e = blockIdx.x * 256 + threadIdx.x;
    if (e < NE_EDGES) {
        int d = ei[NE_EDGES + e];
        int p = atomicAdd(&cursor[d], 1);
        slot_pos[e] = row_start[d] + p;
    }
}

// ---------------------------------------------------------------------------
// Edge prep (CSR slot order). All 8 kidx of an edge pairwise DISTINCT.
// ---------------------------------------------------------------------------
__global__ void edge_prep_sorted(const float* __restrict__ pseudo, const int* __restrict__ ei,
                                 const int* __restrict__ slot_pos,
                                 int* __restrict__ srcs,
                                 float* __restrict__ bas8, unsigned char* __restrict__ kidb) {
    int e = blockIdx.x * 256 + threadIdx.x;
    if (e >= NE_EDGES) return;
    const int ksa[3] = {3, 8, 2};
    float frac[3];
    int id_lo[3], id_hi[3];
#pragma unroll
    for (int d = 0; d < 3; ++d) {
        float u = pseudo[e * 3 + d] * (1.0f / 4.5f);
        u = fminf(fmaxf(u, 0.0f), 1.0f);
        float pos = u * (float)(ksa[d] - 1);
        float fl = floorf(pos);
        int lo = (int)fl;
        frac[d] = pos - fl;
        id_lo[d] = lo;
        id_hi[d] = (lo + 1 <= ksa[d] - 1) ? lo + 1 : lo - 1;
    }
    int j = slot_pos[e];
    srcs[j] = ei[e];
#pragma unroll
    for (int s = 0; s < 8; ++s) {
        float w = 1.0f;
        int k = 0;
        const int strides[3] = {16, 2, 1};
#pragma unroll
        for (int d = 0; d < 3; ++d) {
            int bit = (s >> d) & 1;
            k += (bit ? id_hi[d] : id_lo[d]) * strides[d];
            w *= bit ? frac[d] : (1.0f - frac[d]);
        }
        bas8[(size_t)j * 8 + s] = w;
        kidb[(size_t)j * 8 + s] = (unsigned char)k;
    }
}

// ---------------------------------------------------------------------------
// Layer 1 FUSED (c_in = 1): wave per node; emits bf16 h1.
// ---------------------------------------------------------------------------
__global__ __launch_bounds__(256) void layer1_fused_kernel(
    const int* __restrict__ srcs, const float* __restrict__ bas8,
    const unsigned char* __restrict__ kidb, const int* __restrict__ row_start,
    const float* __restrict__ x, const float* __restrict__ W1,
    const float* __restrict__ root1, const float* __restrict__ b1,
    unsigned short* __restrict__ h1bf) {
    __shared__ float w1s[KTOT * 32];
    __shared__ float scopy[4][8 * 49];
    int tid = threadIdx.x;
    for (int l = tid; l < KTOT * 32; l += 256) w1s[l] = W1[l];
    int w = tid >> 6, lane = tid & 63;
    int n = blockIdx.x * 4 + w;
    bool act = n < NN_NODES;
    float* sc = &scopy[w][0];
    for (int l = lane; l < 8 * 49; l += 64) sc[l] = 0.0f;
    if (act) {
        int beg = row_start[n], end = row_start[n + 1];
        int es = lane >> 3;
        for (int jb = beg; jb < end; jb += 8) {
            int j = jb + es;
            if (j < end) {
                float b = bas8[(size_t)jb * 8 + lane];
                int k = kidb[(size_t)jb * 8 + lane];
                float xv = x[srcs[j]];
                sc[es * 49 + k] += b * xv;
            }
        }
        if (lane < KTOT) {
            float a = 0.0f;
#pragma unroll
            for (int e = 0; e < 8; ++e) a += sc[e * 49 + lane];
            sc[lane] = a;
        }
    }
    __syncthreads();
    if (act && lane < 32) {
        float s = b1[lane] + x[n] * root1[lane];
#pragma unroll 8
        for (int k = 0; k < KTOT; ++k) s = fmaf(sc[k], w1s[k * 32 + lane], s);
        h1bf[n * 32 + lane] = bf16_rne(fmaxf(s, 0.0f));
    }
}

// ---------------------------------------------------------------------------
// Accumulate via MFMA (layers 2 and 3): one wave per node (round-8/9 proven).
// Emits bf16 row [acc(48*CIN) | h_prev(CIN)] -> Kp = 49*CIN.
// ---------------------------------------------------------------------------
#define BTSTRIDE 40
template <int CIN>
__global__ __launch_bounds__(256) void mfma_acc_kernel(
    const int* __restrict__ srcs, const float* __restrict__ bas8,
    const unsigned char* __restrict__ kidb, const int* __restrict__ row_start,
    const unsigned short* __restrict__ hbf, unsigned short* __restrict__ abuf,
    int n0, int mc) {
    constexpr int NT = CIN / 16;
    __shared__ unsigned short BtAll[4][KTOT * BTSTRIDE];
    int w = threadIdx.x >> 6, lane = threadIdx.x & 63;
    int n_local = blockIdx.x * 4 + w;
    if (n_local >= mc) return;
    int n = n0 + n_local;
    unsigned short* Bt = &BtAll[w][0];
    int q = lane >> 4;
    int l15 = lane & 15;
    int beg = row_start[n], end = row_start[n + 1];
    int cnt = end - beg;
    f32x4 acc[3][NT] = {};

    for (int c0 = 0; c0 < cnt; c0 += 32) {
        uint4 z = make_uint4(0, 0, 0, 0);
        for (int l = lane; l < (KTOT * BTSTRIDE) / 8; l += 64) ((uint4*)Bt)[l] = z;
#pragma unroll
        for (int it = 0; it < 4; ++it) {
            int idx = it * 64 + lane;
            int jj = idx >> 3, s = idx & 7;
            int j = c0 + jj;
            if (j < cnt) {
                float b = bas8[(size_t)(beg + j) * 8 + s];
                int k = kidb[(size_t)(beg + j) * 8 + s];
                Bt[k * BTSTRIDE + jj] = bf16_rne(b);
            }
        }
        int srcv[8];
#pragma unroll
        for (int j = 0; j < 8; ++j) {
            int jc = c0 + q * 8 + j;
            jc = (jc < cnt) ? jc : (cnt - 1);
            srcv[j] = srcs[beg + jc];
        }
        bf16x8 afr[3];
#pragma unroll
        for (int mt = 0; mt < 3; ++mt) {
            uint4 raw = *(const uint4*)&Bt[(mt * 16 + l15) * BTSTRIDE + q * 8];
            afr[mt] = __builtin_bit_cast(bf16x8, raw);
        }
#pragma unroll
        for (int nt = 0; nt < NT; ++nt) {
            unsigned int bw[4];
#pragma unroll
            for (int jp = 0; jp < 4; ++jp) {
                unsigned int lo = hbf[(size_t)srcv[2 * jp] * CIN + nt * 16 + l15];
                unsigned int hi = hbf[(size_t)srcv[2 * jp + 1] * CIN + nt * 16 + l15];
                bw[jp] = lo | (hi << 16);
            }
            uint4 braw = make_uint4(bw[0], bw[1], bw[2], bw[3]);
            bf16x8 bfr = __builtin_bit_cast(bf16x8, braw);
#pragma unroll
            for (int mt = 0; mt < 3; ++mt)
                acc[mt][nt] = __builtin_amdgcn_mfma_f32_16x16x32_bf16(afr[mt], bfr,
                                                                      acc[mt][nt], 0, 0, 0);
        }
    }

    unsigned short* arow = abuf + (size_t)n_local * (49 * CIN);
#pragma unroll
    for (int mt = 0; mt < 3; ++mt)
#pragma unroll
        for (int nt = 0; nt < NT; ++nt)
#pragma unroll
            for (int r = 0; r < 4; ++r) {
                int kk = mt * 16 + q * 4 + r;
                int ch = nt * 16 + l15;
                arow[kk * CIN + ch] = bf16_rne(acc[mt][nt][r]);
            }
    if (lane < CIN) arow[KTOT * CIN + lane] = hbf[(size_t)n * CIN + lane];
}

// ---------------------------------------------------------------------------
// Pack W' = [W(KK rows); root(CP rows)] into MFMA B-fragment order.
// ---------------------------------------------------------------------------
__global__ void pack_w_kernel(const float* __restrict__ W, const float* __restrict__ root,
                              int KK, int NN, int total, unsigned short* __restrict__ Wp) {
    int tid = blockIdx.x * 256 + threadIdx.x;
    if (tid >= total) return;
    int nct = NN >> 4;
    int l = tid & 63;
    int c = (tid >> 6) % nct;
    int t = tid / (64 * nct);
    int n = c * 16 + (l & 15);
    int kbase = t * 32 + ((l >> 4) << 3);
    unsigned short vals[8];
#pragma unroll
    for (int jj = 0; jj < 8; ++jj) {
        int k = kbase + jj;
        float v = (k < KK) ? W[(size_t)k * NN + n] : root[(size_t)(k - KK) * NN + n];
        vals[jj] = bf16_rne(v);
    }
    *(uint4*)&Wp[(size_t)tid * 8] = *(uint4*)vals;
}

// ---------------------------------------------------------------------------
// Block-internal K-split MFMA GEMM v2: zero atomics, M=32 rows/block
// (2 row-tiles per wave, B-frags reused), A-prefetch ring depth 2
// (~4 KB A in flight per wave vs 1 KB in v1 -> HBM latency-BW product).
// 4 waves each own a K-quarter; two-phase LDS reduction (33 KB) + fused
// epilogue: LOGSOFTMAX=false -> h2 = bf16(relu(sum+bias));
//           LOGSOFTMAX=true  -> out = log_softmax(relu(sum+bias)).
// ---------------------------------------------------------------------------
template <int NCT, bool LOGSOFTMAX>
__global__ __launch_bounds__(256) void mfma_gemm_block(
    const unsigned short* __restrict__ A, const unsigned short* __restrict__ Wp,
    const float* __restrict__ bias, void* __restrict__ outp,
    int Kp, int n0, int mc) {
    constexpr int NN = NCT * 16;
    constexpr int RSTR = NN + 2;
    __shared__ float red[4][16 * RSTR];
    int w = threadIdx.x >> 6, lane = threadIdx.x & 63;
    int q = lane >> 4, l15 = lane & 15;
    int rl0 = blockIdx.x * 32 + l15;
    int rl1 = rl0 + 16;
    int rc0 = min(rl0, mc - 1);
    int rc1 = min(rl1, mc - 1);
    const unsigned short* arow0 = A + (size_t)rc0 * Kp + (q << 3);
    const unsigned short* arow1 = A + (size_t)rc1 * Kp + (q << 3);
    const uint4* wpq = (const uint4*)Wp;
    f32x4 acc0[NCT] = {};
    f32x4 acc1[NCT] = {};
    int tsteps = Kp >> 5;
    int t0 = (w * tsteps) >> 2;
    int t1 = ((w + 1) * tsteps) >> 2;

    // prologue: A depth-2 ring, B depth-1
    uint4 pA0[2], pA1[2];
    pA0[0] = *(const uint4*)(arow0 + t0 * 32);
    pA1[0] = *(const uint4*)(arow1 + t0 * 32);
    int t0b = (t0 + 1 < t1) ? t0 + 1 : t0;
    pA0[1] = *(const uint4*)(arow0 + t0b * 32);
    pA1[1] = *(const uint4*)(arow1 + t0b * 32);
    uint4 nb[NCT];
    {
        const uint4* bb = wpq + ((size_t)t0 * NCT) * 64 + lane;
#pragma unroll
        for (int c = 0; c < NCT; ++c) nb[c] = bb[c * 64];
    }
    for (int t = t0; t < t1; ++t) {
        int i = (t - t0) & 1;
        uint4 ca0 = pA0[i], ca1 = pA1[i];
        uint4 cb[NCT];
#pragma unroll
        for (int c = 0; c < NCT; ++c) cb[c] = nb[c];
        int tn = (t + 1 < t1) ? t + 1 : t;
        int tn2 = (t + 2 < t1) ? t + 2 : t1 - 1;
        pA0[i] = *(const uint4*)(arow0 + tn2 * 32);
        pA1[i] = *(const uint4*)(arow1 + tn2 * 32);
        const uint4* bbn = wpq + ((size_t)tn * NCT) * 64 + lane;
#pragma unroll
        for (int c = 0; c < NCT; ++c) nb[c] = bbn[c * 64];
        bf16x8 af0 = __builtin_bit_cast(bf16x8, ca0);
        bf16x8 af1 = __builtin_bit_cast(bf16x8, ca1);
#pragma unroll
        for (int c = 0; c < NCT; ++c) {
            bf16x8 bfr = __builtin_bit_cast(bf16x8, cb[c]);
            acc0[c] = __builtin_amdgcn_mfma_f32_16x16x32_bf16(af0, bfr, acc0[c], 0, 0, 0);
            acc1[c] = __builtin_amdgcn_mfma_f32_16x16x32_bf16(af1, bfr, acc1[c], 0, 0, 0);
        }
    }

    // two-phase reduction + epilogue (16 rows per phase)
    float* myred = &red[w][0];
#pragma unroll
    for (int phase = 0; phase < 2; ++phase) {
        if (phase == 1) __syncthreads();   // protect LDS reuse
#pragma unroll
        for (int c = 0; c < NCT; ++c)
#pragma unroll
            for (int r = 0; r < 4; ++r)
                myred[(q * 4 + r) * RSTR + c * 16 + l15] =
                    phase == 0 ? acc0[c][r] : acc1[c][r];
        __syncthreads();
        int rowbase = blockIdx.x * 32 + phase * 16;
        if (!LOGSOFTMAX) {
            unsigned short* outb = (unsigned short*)outp;
            for (int l = threadIdx.x; l < 16 * NN; l += 256) {
                int row = l / NN, col = l % NN;
                int idx = row * RSTR + col;
                float v = red[0][idx] + red[1][idx] + red[2][idx] + red[3][idx];
                v = fmaxf(v + bias[col], 0.0f);
                int ro = rowbase + row;
                if (ro < mc) outb[(size_t)(n0 + ro) * NN + col] = bf16_rne(v);
            }
        } else {
            float* outf = (float*)outp;
            int row = threadIdx.x >> 4;
            int cb0 = threadIdx.x & 15;
            float v[8];
            float mx = -1e30f;
#pragma unroll
            for (int c = 0; c < 8; ++c) {
                int col = cb0 + c * 16;
                int idx = row * RSTR + col;
                float s = red[0][idx] + red[1][idx] + red[2][idx] + red[3][idx];
                s = fmaxf(s + bias[col], 0.0f);
                v[c] = s;
                mx = fmaxf(mx, s);
            }
#pragma unroll
            for (int off = 8; off > 0; off >>= 1) mx = fmaxf(mx, __shfl_xor(mx, off));
            float se = 0.0f;
#pragma unroll
            for (int c = 0; c < 8; ++c) se += expf(v[c] - mx);
#pragma unroll
            for (int off = 8; off > 0; off >>= 1) se += __shfl_xor(se, off);
            float lse = mx + logf(se);
            int ro = rowbase + row;
            if (ro < mc) {
#pragma unroll
                for (int c = 0; c < 8; ++c)
                    outf[(size_t)(n0 + ro) * 128 + cb0 + c * 16] = v[c] - lse;
            }
        }
    }
}

// ---------------------------------------------------------------------------
// Launch
// ---------------------------------------------------------------------------
extern "C" void kernel_launch(void* const* d_in, const int* in_sizes, int n_in,
                              void* d_out, int out_size, void* d_ws, size_t ws_size,
                              hipStream_t stream) {
    const float* x = (const float*)d_in[0];
    const int* ei = (const int*)d_in[1];
    const float* pseudo = (const float*)d_in[2];
    const float* W1 = (const float*)d_in[3];
    const float* root1 = (const float*)d_in[4];
    const float* b1 = (const float*)d_in[5];
    const float* W2 = (const float*)d_in[6];
    const float* root2 = (const float*)d_in[7];
    const float* b2 = (const float*)d_in[8];
    const float* W3 = (const float*)d_in[9];
    const float* root3 = (const float*)d_in[10];
    const float* b3 = (const float*)d_in[11];
    float* out = (float*)d_out;
    char* ws = (char*)d_ws;

    const int N = NN_NODES, E = NE_EDGES;
    const int Kp2 = 49 * 32;   // 1568
    const int Kp3 = 49 * 64;   // 3136
    size_t off = 0;
    auto carve = [&](size_t bytes) {
        size_t p = off;
        off += (bytes + 255) & ~(size_t)255;
        return p;
    };
    int* counts = (int*)(ws + carve((size_t)N * 4 * 2));
    int* cursor = counts + N;
    int* row_start = (int*)(ws + carve((size_t)(N + 1) * 4));
    int* slot_pos = (int*)(ws + carve((size_t)E * 4));
    int* srcs = (int*)(ws + carve((size_t)E * 4));
    float* bas8 = (float*)(ws + carve((size_t)E * 8 * 4));
    unsigned char* kidb = (unsigned char*)(ws + carve((size_t)E * 8));
    unsigned short* h1bf = (unsigned short*)(ws + carve((size_t)N * 32 * 2));
    unsigned short* h2bf = (unsigned short*)(ws + carve((size_t)N * 64 * 2));
    unsigned short* Wp2 = (unsigned short*)(ws + carve((size_t)Kp2 * 64 * 2));
    unsigned short* Wp3 = (unsigned short*)(ws + carve((size_t)Kp3 * 128 * 2));
    size_t rem = (ws_size > off) ? (ws_size - off) : 0;
    unsigned short* abuf = (unsigned short*)(ws + off);

    int ch2 = (int)(rem / ((size_t)Kp2 * 2));
    int ch3 = (int)(rem / ((size_t)Kp3 * 2));
    if (ch2 > N) ch2 = N;
    if (ch3 > N) ch3 = N;
    if (ch2 < 1) ch2 = 1;
    if (ch3 < 1) ch3 = 1;

    int egrid = (E + 255) / 256;

    // CSR + sorted edge metadata
    zero_kernel<<<(2 * N + 255) / 256, 256, 0, stream>>>(counts, 2 * N);
    count_kernel<<<egrid, 256, 0, stream>>>(ei, counts);
    scan_kernel<<<1, 256, 0, stream>>>(counts, row_start);
    fill_kernel<<<egrid, 256, 0, stream>>>(ei, row_start, cursor, slot_pos);
    edge_prep_sorted<<<egrid, 256, 0, stream>>>(pseudo, ei, slot_pos, srcs, bas8, kidb);

    // pack weights (bf16 MFMA B-fragment order)
    int tot2 = (Kp2 / 32) * (64 / 16) * 64;
    int tot3 = (Kp3 / 32) * (128 / 16) * 64;
    pack_w_kernel<<<(tot2 + 255) / 256, 256, 0, stream>>>(W2, root2, KTOT * 32, 64, tot2, Wp2);
    pack_w_kernel<<<(tot3 + 255) / 256, 256, 0, stream>>>(W3, root3, KTOT * 64, 128, tot3, Wp3);

    // layer 1 (fused accumulate + dense + relu) -> bf16 h1
    layer1_fused_kernel<<<(N + 3) / 4, 256, 0, stream>>>(srcs, bas8, kidb, row_start, x,
                                                         W1, root1, b1, h1bf);

    // layer 2 (MFMA accumulate -> block-K-split GEMM v2, fused bias+relu+bf16)
    for (int n0 = 0; n0 < N; n0 += ch2) {
        int mc = N - n0 < ch2 ? N - n0 : ch2;
        mfma_acc_kernel<32><<<(mc + 3) / 4, 256, 0, stream>>>(
            srcs, bas8, kidb, row_start, h1bf, abuf, n0, mc);
        mfma_gemm_block<4, false><<<(mc + 31) / 32, 256, 0, stream>>>(
            abuf, Wp2, b2, h2bf, Kp2, n0, mc);
    }

    // layer 3 (MFMA accumulate -> block-K-split GEMM v2, fused epilogue)
    for (int n0 = 0; n0 < N; n0 += ch3) {
        int mc = N - n0 < ch3 ? N - n0 : ch3;
        mfma_acc_kernel<64><<<(mc + 3) / 4, 256, 0, stream>>>(
            srcs, bas8, kidb, row_start, h2bf, abuf, n0, mc);
        mfma_gemm_block<8, true><<<(mc + 31) / 32, 256, 0, stream>>>(
            abuf, Wp3, b3, out, Kp3, n0, mc);
    }
}

// Round 15
// 346.586 us; speedup vs baseline: 1.0886x; 1.0886x over previous
//
#include <hip/hip_runtime.h>
#include <hip/hip_bf16.h>

#define NN_NODES 20000
#define NE_EDGES 500000
#define KTOT 48

typedef __bf16 bf16x8 __attribute__((ext_vector_type(8)));
typedef float f32x4 __attribute__((ext_vector_type(4)));

__device__ inline unsigned short bf16_rne(float x) {
    unsigned int u = __float_as_uint(x);
    u = (u + 0x7fffu + ((u >> 16) & 1u)) >> 16;
    return (unsigned short)u;
}

// ---------------------------------------------------------------------------
// Zero helper
// ---------------------------------------------------------------------------
__global__ void zero_kernel(int* __restrict__ p, int n) {
    int i = blockIdx.x * 256 + threadIdx.x;
    if (i < n) p[i] = 0;
}

// ---------------------------------------------------------------------------
// CSR build
// ---------------------------------------------------------------------------
__global__ void count_kernel(const int* __restrict__ ei, int* __restrict__ counts) {
    int e = blockIdx.x * 256 + threadIdx.x;
    if (e < NE_EDGES) atomicAdd(&counts[ei[NE_EDGES + e]], 1);
}

__global__ void scan_kernel(const int* __restrict__ counts, int* __restrict__ row_start) {
    __shared__ int part[256];
    const int CH = (NN_NODES + 255) / 256;
    int t = threadIdx.x;
    int begin = t * CH;
    int end = begin + CH;
    if (end > NN_NODES) end = NN_NODES;
    int sum = 0;
    for (int i = begin; i < end && i < NN_NODES; ++i) sum += counts[i];
    part[t] = sum;
    __syncthreads();
    for (int off = 1; off < 256; off <<= 1) {
        int v = (t >= off) ? part[t - off] : 0;
        __syncthreads();
        part[t] += v;
        __syncthreads();
    }
    int run = (t == 0) ? 0 : part[t - 1];
    for (int i = begin; i < end && i < NN_NODES; ++i) {
        row_start[i] = run;
        run += counts[i];
    }
    if (t == 255) row_start[NN_NODES] = part[255];
}

__global__ void fill_kernel(const int* __restrict__ ei, const int* __restrict__ row_start,
                            int* __restrict__ cursor, int* __restrict__ slot_pos) {
    int e = blockIdx.x * 256 + threadIdx.x;
    if (e < NE_EDGES) {
        int d = ei[NE_EDGES + e];
        int p = atomicAdd(&cursor[d], 1);
        slot_pos[e] = row_start[d] + p;
    }
}

// ---------------------------------------------------------------------------
// Edge prep (CSR slot order). All 8 kidx of an edge pairwise DISTINCT.
// ---------------------------------------------------------------------------
__global__ void edge_prep_sorted(const float* __restrict__ pseudo, const int* __restrict__ ei,
                                 const int* __restrict__ slot_pos,
                                 int* __restrict__ srcs,
                                 float* __restrict__ bas8, unsigned char* __restrict__ kidb) {
    int e = blockIdx.x * 256 + threadIdx.x;
    if (e >= NE_EDGES) return;
    const int ksa[3] = {3, 8, 2};
    float frac[3];
    int id_lo[3], id_hi[3];
#pragma unroll
    for (int d = 0; d < 3; ++d) {
        float u = pseudo[e * 3 + d] * (1.0f / 4.5f);
        u = fminf(fmaxf(u, 0.0f), 1.0f);
        float pos = u * (float)(ksa[d] - 1);
        float fl = floorf(pos);
        int lo = (int)fl;
        frac[d] = pos - fl;
        id_lo[d] = lo;
        id_hi[d] = (lo + 1 <= ksa[d] - 1) ? lo + 1 : lo - 1;
    }
    int j = slot_pos[e];
    srcs[j] = ei[e];
#pragma unroll
    for (int s = 0; s < 8; ++s) {
        float w = 1.0f;
        int k = 0;
        const int strides[3] = {16, 2, 1};
#pragma unroll
        for (int d = 0; d < 3; ++d) {
            int bit = (s >> d) & 1;
            k += (bit ? id_hi[d] : id_lo[d]) * strides[d];
            w *= bit ? frac[d] : (1.0f - frac[d]);
        }
        bas8[(size_t)j * 8 + s] = w;
        kidb[(size_t)j * 8 + s] = (unsigned char)k;
    }
}

// ---------------------------------------------------------------------------
// Layer 1 FUSED (c_in = 1): wave per node; emits bf16 h1.
// ---------------------------------------------------------------------------
__global__ __launch_bounds__(256) void layer1_fused_kernel(
    const int* __restrict__ srcs, const float* __restrict__ bas8,
    const unsigned char* __restrict__ kidb, const int* __restrict__ row_start,
    const float* __restrict__ x, const float* __restrict__ W1,
    const float* __restrict__ root1, const float* __restrict__ b1,
    unsigned short* __restrict__ h1bf) {
    __shared__ float w1s[KTOT * 32];
    __shared__ float scopy[4][8 * 49];
    int tid = threadIdx.x;
    for (int l = tid; l < KTOT * 32; l += 256) w1s[l] = W1[l];
    int w = tid >> 6, lane = tid & 63;
    int n = blockIdx.x * 4 + w;
    bool act = n < NN_NODES;
    float* sc = &scopy[w][0];
    for (int l = lane; l < 8 * 49; l += 64) sc[l] = 0.0f;
    if (act) {
        int beg = row_start[n], end = row_start[n + 1];
        int es = lane >> 3;
        for (int jb = beg; jb < end; jb += 8) {
            int j = jb + es;
            if (j < end) {
                float b = bas8[(size_t)jb * 8 + lane];
                int k = kidb[(size_t)jb * 8 + lane];
                float xv = x[srcs[j]];
                sc[es * 49 + k] += b * xv;
            }
        }
        if (lane < KTOT) {
            float a = 0.0f;
#pragma unroll
            for (int e = 0; e < 8; ++e) a += sc[e * 49 + lane];
            sc[lane] = a;
        }
    }
    __syncthreads();
    if (act && lane < 32) {
        float s = b1[lane] + x[n] * root1[lane];
#pragma unroll 8
        for (int k = 0; k < KTOT; ++k) s = fmaf(sc[k], w1s[k * 32 + lane], s);
        h1bf[n * 32 + lane] = bf16_rne(fmaxf(s, 0.0f));
    }
}

// ---------------------------------------------------------------------------
// Accumulate via MFMA (layers 2 and 3): one wave per node (round-8/9 proven).
// Emits bf16 row [acc(48*CIN) | h_prev(CIN)] -> Kp = 49*CIN.
// ---------------------------------------------------------------------------
#define BTSTRIDE 40
template <int CIN>
__global__ __launch_bounds__(256) void mfma_acc_kernel(
    const int* __restrict__ srcs, const float* __restrict__ bas8,
    const unsigned char* __restrict__ kidb, const int* __restrict__ row_start,
    const unsigned short* __restrict__ hbf, unsigned short* __restrict__ abuf,
    int n0, int mc) {
    constexpr int NT = CIN / 16;
    __shared__ unsigned short BtAll[4][KTOT * BTSTRIDE];
    int w = threadIdx.x >> 6, lane = threadIdx.x & 63;
    int n_local = blockIdx.x * 4 + w;
    if (n_local >= mc) return;
    int n = n0 + n_local;
    unsigned short* Bt = &BtAll[w][0];
    int q = lane >> 4;
    int l15 = lane & 15;
    int beg = row_start[n], end = row_start[n + 1];
    int cnt = end - beg;
    f32x4 acc[3][NT] = {};

    for (int c0 = 0; c0 < cnt; c0 += 32) {
        uint4 z = make_uint4(0, 0, 0, 0);
        for (int l = lane; l < (KTOT * BTSTRIDE) / 8; l += 64) ((uint4*)Bt)[l] = z;
#pragma unroll
        for (int it = 0; it < 4; ++it) {
            int idx = it * 64 + lane;
            int jj = idx >> 3, s = idx & 7;
            int j = c0 + jj;
            if (j < cnt) {
                float b = bas8[(size_t)(beg + j) * 8 + s];
                int k = kidb[(size_t)(beg + j) * 8 + s];
                Bt[k * BTSTRIDE + jj] = bf16_rne(b);
            }
        }
        int srcv[8];
#pragma unroll
        for (int j = 0; j < 8; ++j) {
            int jc = c0 + q * 8 + j;
            jc = (jc < cnt) ? jc : (cnt - 1);
            srcv[j] = srcs[beg + jc];
        }
        bf16x8 afr[3];
#pragma unroll
        for (int mt = 0; mt < 3; ++mt) {
            uint4 raw = *(const uint4*)&Bt[(mt * 16 + l15) * BTSTRIDE + q * 8];
            afr[mt] = __builtin_bit_cast(bf16x8, raw);
        }
#pragma unroll
        for (int nt = 0; nt < NT; ++nt) {
            unsigned int bw[4];
#pragma unroll
            for (int jp = 0; jp < 4; ++jp) {
                unsigned int lo = hbf[(size_t)srcv[2 * jp] * CIN + nt * 16 + l15];
                unsigned int hi = hbf[(size_t)srcv[2 * jp + 1] * CIN + nt * 16 + l15];
                bw[jp] = lo | (hi << 16);
            }
            uint4 braw = make_uint4(bw[0], bw[1], bw[2], bw[3]);
            bf16x8 bfr = __builtin_bit_cast(bf16x8, braw);
#pragma unroll
            for (int mt = 0; mt < 3; ++mt)
                acc[mt][nt] = __builtin_amdgcn_mfma_f32_16x16x32_bf16(afr[mt], bfr,
                                                                      acc[mt][nt], 0, 0, 0);
        }
    }

    unsigned short* arow = abuf + (size_t)n_local * (49 * CIN);
#pragma unroll
    for (int mt = 0; mt < 3; ++mt)
#pragma unroll
        for (int nt = 0; nt < NT; ++nt)
#pragma unroll
            for (int r = 0; r < 4; ++r) {
                int kk = mt * 16 + q * 4 + r;
                int ch = nt * 16 + l15;
                arow[kk * CIN + ch] = bf16_rne(acc[mt][nt][r]);
            }
    if (lane < CIN) arow[KTOT * CIN + lane] = hbf[(size_t)n * CIN + lane];
}

// ---------------------------------------------------------------------------
// Pack W' = [W(KK rows); root(CP rows)] into MFMA B-fragment order.
// ---------------------------------------------------------------------------
__global__ void pack_w_kernel(const float* __restrict__ W, const float* __restrict__ root,
                              int KK, int NN, int total, unsigned short* __restrict__ Wp) {
    int tid = blockIdx.x * 256 + threadIdx.x;
    if (tid >= total) return;
    int nct = NN >> 4;
    int l = tid & 63;
    int c = (tid >> 6) % nct;
    int t = tid / (64 * nct);
    int n = c * 16 + (l & 15);
    int kbase = t * 32 + ((l >> 4) << 3);
    unsigned short vals[8];
#pragma unroll
    for (int jj = 0; jj < 8; ++jj) {
        int k = kbase + jj;
        float v = (k < KK) ? W[(size_t)k * NN + n] : root[(size_t)(k - KK) * NN + n];
        vals[jj] = bf16_rne(v);
    }
    *(uint4*)&Wp[(size_t)tid * 8] = *(uint4*)vals;
}

// ---------------------------------------------------------------------------
// Block-internal K-split MFMA GEMM v3: zero atomics, M=16 rows/block,
// NW waves per block each owning a K-slice (per-wave body identical to the
// proven R13 kernel: depth-1 pipeline, VGPR ~52, no spill). NW=8 for layer 3
// doubles resident waves -> 2x in-flight A-bytes vs R13. LDS reduction over
// NW partials + fused epilogue:
//   LOGSOFTMAX=false: h2 = bf16(relu(sum + bias))
//   LOGSOFTMAX=true : out = log_softmax(relu(sum + bias)) (fp32, 128 cols)
// ---------------------------------------------------------------------------
template <int NCT, int NW, bool LOGSOFTMAX>
__global__ __launch_bounds__(NW * 64) void mfma_gemm_block(
    const unsigned short* __restrict__ A, const unsigned short* __restrict__ Wp,
    const float* __restrict__ bias, void* __restrict__ outp,
    int Kp, int n0, int mc) {
    constexpr int NN = NCT * 16;
    constexpr int RSTR = NN + 2;   // padded row stride (floats)
    __shared__ float red[NW][16 * RSTR];
    int w = threadIdx.x >> 6, lane = threadIdx.x & 63;
    int q = lane >> 4, l15 = lane & 15;
    int row_local = blockIdx.x * 16 + l15;
    int row_c = min(row_local, mc - 1);
    const unsigned short* arow = A + (size_t)row_c * Kp + (q << 3);
    const uint4* wpq = (const uint4*)Wp;
    f32x4 acc[NCT] = {};
    int tsteps = Kp >> 5;
    int t0 = (w * tsteps) / NW;
    int t1 = ((w + 1) * tsteps) / NW;

    // prologue prefetch (depth 1, proven no-spill shape)
    uint4 na = *(const uint4*)(arow + t0 * 32);
    uint4 nb[NCT];
    {
        const uint4* bb = wpq + ((size_t)t0 * NCT) * 64 + lane;
#pragma unroll
        for (int c = 0; c < NCT; ++c) nb[c] = bb[c * 64];
    }
    for (int t = t0; t < t1; ++t) {
        uint4 ca = na;
        uint4 cb[NCT];
#pragma unroll
        for (int c = 0; c < NCT; ++c) cb[c] = nb[c];
        int tn = (t + 1 < t1) ? t + 1 : t;   // clamped (harmless reload on last)
        na = *(const uint4*)(arow + tn * 32);
        const uint4* bb = wpq + ((size_t)tn * NCT) * 64 + lane;
#pragma unroll
        for (int c = 0; c < NCT; ++c) nb[c] = bb[c * 64];
        bf16x8 af = __builtin_bit_cast(bf16x8, ca);
#pragma unroll
        for (int c = 0; c < NCT; ++c) {
            bf16x8 bfr = __builtin_bit_cast(bf16x8, cb[c]);
            acc[c] = __builtin_amdgcn_mfma_f32_16x16x32_bf16(af, bfr, acc[c], 0, 0, 0);
        }
    }

    // stage partials: C-layout row = q*4+r, col = c*16+l15
    float* myred = &red[w][0];
#pragma unroll
    for (int c = 0; c < NCT; ++c)
#pragma unroll
        for (int r = 0; r < 4; ++r)
            myred[(q * 4 + r) * RSTR + c * 16 + l15] = acc[c][r];
    __syncthreads();

    if (!LOGSOFTMAX) {
        // layer 2 epilogue: 16 x NN elems, coalesced
        unsigned short* outb = (unsigned short*)outp;
        for (int l = threadIdx.x; l < 16 * NN; l += NW * 64) {
            int row = l / NN, col = l % NN;
            int idx = row * RSTR + col;
            float v = 0.0f;
#pragma unroll
            for (int i = 0; i < NW; ++i) v += red[i][idx];
            v = fmaxf(v + bias[col], 0.0f);
            int ro = blockIdx.x * 16 + row;
            if (ro < mc) outb[(size_t)(n0 + ro) * NN + col] = bf16_rne(v);
        }
    } else {
        // layer 3 epilogue: 16 threads per row, 8 cols each, fused log_softmax
        if (threadIdx.x < 256) {
            float* outf = (float*)outp;
            int row = threadIdx.x >> 4;
            int cb0 = threadIdx.x & 15;
            float v[8];
            float mx = -1e30f;
#pragma unroll
            for (int c = 0; c < 8; ++c) {
                int col = cb0 + c * 16;
                int idx = row * RSTR + col;
                float s = 0.0f;
#pragma unroll
                for (int i = 0; i < NW; ++i) s += red[i][idx];
                s = fmaxf(s + bias[col], 0.0f);
                v[c] = s;
                mx = fmaxf(mx, s);
            }
#pragma unroll
            for (int off = 8; off > 0; off >>= 1) mx = fmaxf(mx, __shfl_xor(mx, off));
            float se = 0.0f;
#pragma unroll
            for (int c = 0; c < 8; ++c) se += expf(v[c] - mx);
#pragma unroll
            for (int off = 8; off > 0; off >>= 1) se += __shfl_xor(se, off);
            float lse = mx + logf(se);
            int ro = blockIdx.x * 16 + row;
            if (ro < mc) {
#pragma unroll
                for (int c = 0; c < 8; ++c)
                    outf[(size_t)(n0 + ro) * 128 + cb0 + c * 16] = v[c] - lse;
            }
        }
    }
}

// ---------------------------------------------------------------------------
// Launch
// ---------------------------------------------------------------------------
extern "C" void kernel_launch(void* const* d_in, const int* in_sizes, int n_in,
                              void* d_out, int out_size, void* d_ws, size_t ws_size,
                              hipStream_t stream) {
    const float* x = (const float*)d_in[0];
    const int* ei = (const int*)d_in[1];
    const float* pseudo = (const float*)d_in[2];
    const float* W1 = (const float*)d_in[3];
    const float* root1 = (const float*)d_in[4];
    const float* b1 = (const float*)d_in[5];
    const float* W2 = (const float*)d_in[6];
    const float* root2 = (const float*)d_in[7];
    const float* b2 = (const float*)d_in[8];
    const float* W3 = (const float*)d_in[9];
    const float* root3 = (const float*)d_in[10];
    const float* b3 = (const float*)d_in[11];
    float* out = (float*)d_out;
    char* ws = (char*)d_ws;

    const int N = NN_NODES, E = NE_EDGES;
    const int Kp2 = 49 * 32;   // 1568
    const int Kp3 = 49 * 64;   // 3136
    size_t off = 0;
    auto carve = [&](size_t bytes) {
        size_t p = off;
        off += (bytes + 255) & ~(size_t)255;
        return p;
    };
    int* counts = (int*)(ws + carve((size_t)N * 4 * 2));
    int* cursor = counts + N;
    int* row_start = (int*)(ws + carve((size_t)(N + 1) * 4));
    int* slot_pos = (int*)(ws + carve((size_t)E * 4));
    int* srcs = (int*)(ws + carve((size_t)E * 4));
    float* bas8 = (float*)(ws + carve((size_t)E * 8 * 4));
    unsigned char* kidb = (unsigned char*)(ws + carve((size_t)E * 8));
    unsigned short* h1bf = (unsigned short*)(ws + carve((size_t)N * 32 * 2));
    unsigned short* h2bf = (unsigned short*)(ws + carve((size_t)N * 64 * 2));
    unsigned short* Wp2 = (unsigned short*)(ws + carve((size_t)Kp2 * 64 * 2));
    unsigned short* Wp3 = (unsigned short*)(ws + carve((size_t)Kp3 * 128 * 2));
    size_t rem = (ws_size > off) ? (ws_size - off) : 0;
    unsigned short* abuf = (unsigned short*)(ws + off);

    int ch2 = (int)(rem / ((size_t)Kp2 * 2));
    int ch3 = (int)(rem / ((size_t)Kp3 * 2));
    if (ch2 > N) ch2 = N;
    if (ch3 > N) ch3 = N;
    if (ch2 < 1) ch2 = 1;
    if (ch3 < 1) ch3 = 1;

    int egrid = (E + 255) / 256;

    // CSR + sorted edge metadata
    zero_kernel<<<(2 * N + 255) / 256, 256, 0, stream>>>(counts, 2 * N);
    count_kernel<<<egrid, 256, 0, stream>>>(ei, counts);
    scan_kernel<<<1, 256, 0, stream>>>(counts, row_start);
    fill_kernel<<<egrid, 256, 0, stream>>>(ei, row_start, cursor, slot_pos);
    edge_prep_sorted<<<egrid, 256, 0, stream>>>(pseudo, ei, slot_pos, srcs, bas8, kidb);

    // pack weights (bf16 MFMA B-fragment order)
    int tot2 = (Kp2 / 32) * (64 / 16) * 64;
    int tot3 = (Kp3 / 32) * (128 / 16) * 64;
    pack_w_kernel<<<(tot2 + 255) / 256, 256, 0, stream>>>(W2, root2, KTOT * 32, 64, tot2, Wp2);
    pack_w_kernel<<<(tot3 + 255) / 256, 256, 0, stream>>>(W3, root3, KTOT * 64, 128, tot3, Wp3);

    // layer 1 (fused accumulate + dense + relu) -> bf16 h1
    layer1_fused_kernel<<<(N + 3) / 4, 256, 0, stream>>>(srcs, bas8, kidb, row_start, x,
                                                         W1, root1, b1, h1bf);

    // layer 2 (MFMA accumulate -> block-K-split GEMM, NW=4)
    for (int n0 = 0; n0 < N; n0 += ch2) {
        int mc = N - n0 < ch2 ? N - n0 : ch2;
        mfma_acc_kernel<32><<<(mc + 3) / 4, 256, 0, stream>>>(
            srcs, bas8, kidb, row_start, h1bf, abuf, n0, mc);
        mfma_gemm_block<4, 4, false><<<(mc + 15) / 16, 256, 0, stream>>>(
            abuf, Wp2, b2, h2bf, Kp2, n0, mc);
    }

    // layer 3 (MFMA accumulate -> block-K-split GEMM, NW=8: 2x in-flight A)
    for (int n0 = 0; n0 < N; n0 += ch3) {
        int mc = N - n0 < ch3 ? N - n0 : ch3;
        mfma_acc_kernel<64><<<(mc + 3) / 4, 256, 0, stream>>>(
            srcs, bas8, kidb, row_start, h2bf, abuf, n0, mc);
        mfma_gemm_block<8, 8, true><<<(mc + 15) / 16, 512, 0, stream>>>(
            abuf, Wp3, b3, out, Kp3, n0, mc);
    }
}

// Round 16
// 324.784 us; speedup vs baseline: 1.1617x; 1.0671x over previous
//
#include <hip/hip_runtime.h>
#include <hip/hip_bf16.h>

#define NN_NODES 20000
#define NE_EDGES 500000
#define KTOT 48

typedef __bf16 bf16x8 __attribute__((ext_vector_type(8)));
typedef float f32x4 __attribute__((ext_vector_type(4)));

__device__ inline unsigned short bf16_rne(float x) {
    unsigned int u = __float_as_uint(x);
    u = (u + 0x7fffu + ((u >> 16) & 1u)) >> 16;
    return (unsigned short)u;
}

// ---------------------------------------------------------------------------
// Zero helper
// ---------------------------------------------------------------------------
__global__ void zero_kernel(int* __restrict__ p, int n) {
    int i = blockIdx.x * 256 + threadIdx.x;
    if (i < n) p[i] = 0;
}

// ---------------------------------------------------------------------------
// CSR build
// ---------------------------------------------------------------------------
__global__ void count_kernel(const int* __restrict__ ei, int* __restrict__ counts) {
    int e = blockIdx.x * 256 + threadIdx.x;
    if (e < NE_EDGES) atomicAdd(&counts[ei[NE_EDGES + e]], 1);
}

__global__ void scan_kernel(const int* __restrict__ counts, int* __restrict__ row_start) {
    __shared__ int part[256];
    const int CH = (NN_NODES + 255) / 256;
    int t = threadIdx.x;
    int begin = t * CH;
    int end = begin + CH;
    if (end > NN_NODES) end = NN_NODES;
    int sum = 0;
    for (int i = begin; i < end && i < NN_NODES; ++i) sum += counts[i];
    part[t] = sum;
    __syncthreads();
    for (int off = 1; off < 256; off <<= 1) {
        int v = (t >= off) ? part[t - off] : 0;
        __syncthreads();
        part[t] += v;
        __syncthreads();
    }
    int run = (t == 0) ? 0 : part[t - 1];
    for (int i = begin; i < end && i < NN_NODES; ++i) {
        row_start[i] = run;
        run += counts[i];
    }
    if (t == 255) row_start[NN_NODES] = part[255];
}

__global__ void fill_kernel(const int* __restrict__ ei, const int* __restrict__ row_start,
                            int* __restrict__ cursor, int* __restrict__ slot_pos) {
    int e = blockIdx.x * 256 + threadIdx.x;
    if (e < NE_EDGES) {
        int d = ei[NE_EDGES + e];
        int p = atomicAdd(&cursor[d], 1);
        slot_pos[e] = row_start[d] + p;
    }
}

// ---------------------------------------------------------------------------
// Edge prep (CSR slot order). All 8 kidx of an edge pairwise DISTINCT.
// ---------------------------------------------------------------------------
__global__ void edge_prep_sorted(const float* __restrict__ pseudo, const int* __restrict__ ei,
                                 const int* __restrict__ slot_pos,
                                 int* __restrict__ srcs,
                                 float* __restrict__ bas8, unsigned char* __restrict__ kidb) {
    int e = blockIdx.x * 256 + threadIdx.x;
    if (e >= NE_EDGES) return;
    const int ksa[3] = {3, 8, 2};
    float frac[3];
    int id_lo[3], id_hi[3];
#pragma unroll
    for (int d = 0; d < 3; ++d) {
        float u = pseudo[e * 3 + d] * (1.0f / 4.5f);
        u = fminf(fmaxf(u, 0.0f), 1.0f);
        float pos = u * (float)(ksa[d] - 1);
        float fl = floorf(pos);
        int lo = (int)fl;
        frac[d] = pos - fl;
        id_lo[d] = lo;
        id_hi[d] = (lo + 1 <= ksa[d] - 1) ? lo + 1 : lo - 1;
    }
    int j = slot_pos[e];
    srcs[j] = ei[e];
#pragma unroll
    for (int s = 0; s < 8; ++s) {
        float w = 1.0f;
        int k = 0;
        const int strides[3] = {16, 2, 1};
#pragma unroll
        for (int d = 0; d < 3; ++d) {
            int bit = (s >> d) & 1;
            k += (bit ? id_hi[d] : id_lo[d]) * strides[d];
            w *= bit ? frac[d] : (1.0f - frac[d]);
        }
        bas8[(size_t)j * 8 + s] = w;
        kidb[(size_t)j * 8 + s] = (unsigned char)k;
    }
}

// ---------------------------------------------------------------------------
// Layer 1 FUSED (c_in = 1): wave per node; emits bf16 h1.
// ---------------------------------------------------------------------------
__global__ __launch_bounds__(256) void layer1_fused_kernel(
    const int* __restrict__ srcs, const float* __restrict__ bas8,
    const unsigned char* __restrict__ kidb, const int* __restrict__ row_start,
    const float* __restrict__ x, const float* __restrict__ W1,
    const float* __restrict__ root1, const float* __restrict__ b1,
    unsigned short* __restrict__ h1bf) {
    __shared__ float w1s[KTOT * 32];
    __shared__ float scopy[4][8 * 49];
    int tid = threadIdx.x;
    for (int l = tid; l < KTOT * 32; l += 256) w1s[l] = W1[l];
    int w = tid >> 6, lane = tid & 63;
    int n = blockIdx.x * 4 + w;
    bool act = n < NN_NODES;
    float* sc = &scopy[w][0];
    for (int l = lane; l < 8 * 49; l += 64) sc[l] = 0.0f;
    if (act) {
        int beg = row_start[n], end = row_start[n + 1];
        int es = lane >> 3;
        for (int jb = beg; jb < end; jb += 8) {
            int j = jb + es;
            if (j < end) {
                float b = bas8[(size_t)jb * 8 + lane];
                int k = kidb[(size_t)jb * 8 + lane];
                float xv = x[srcs[j]];
                sc[es * 49 + k] += b * xv;
            }
        }
        if (lane < KTOT) {
            float a = 0.0f;
#pragma unroll
            for (int e = 0; e < 8; ++e) a += sc[e * 49 + lane];
            sc[lane] = a;
        }
    }
    __syncthreads();
    if (act && lane < 32) {
        float s = b1[lane] + x[n] * root1[lane];
#pragma unroll 8
        for (int k = 0; k < KTOT; ++k) s = fmaf(sc[k], w1s[k * 32 + lane], s);
        h1bf[n * 32 + lane] = bf16_rne(fmaxf(s, 0.0f));
    }
}

// ---------------------------------------------------------------------------
// Accumulate via MFMA (layer 2): one wave per node (round-8/9 proven).
// Emits bf16 row [acc(48*32) | h_prev(32)] -> Kp2 = 49*32.
// ---------------------------------------------------------------------------
#define BTSTRIDE 40
template <int CIN>
__global__ __launch_bounds__(256) void mfma_acc_kernel(
    const int* __restrict__ srcs, const float* __restrict__ bas8,
    const unsigned char* __restrict__ kidb, const int* __restrict__ row_start,
    const unsigned short* __restrict__ hbf, unsigned short* __restrict__ abuf,
    int n0, int mc) {
    constexpr int NT = CIN / 16;
    __shared__ unsigned short BtAll[4][KTOT * BTSTRIDE];
    int w = threadIdx.x >> 6, lane = threadIdx.x & 63;
    int n_local = blockIdx.x * 4 + w;
    if (n_local >= mc) return;
    int n = n0 + n_local;
    unsigned short* Bt = &BtAll[w][0];
    int q = lane >> 4;
    int l15 = lane & 15;
    int beg = row_start[n], end = row_start[n + 1];
    int cnt = end - beg;
    f32x4 acc[3][NT] = {};

    for (int c0 = 0; c0 < cnt; c0 += 32) {
        uint4 z = make_uint4(0, 0, 0, 0);
        for (int l = lane; l < (KTOT * BTSTRIDE) / 8; l += 64) ((uint4*)Bt)[l] = z;
#pragma unroll
        for (int it = 0; it < 4; ++it) {
            int idx = it * 64 + lane;
            int jj = idx >> 3, s = idx & 7;
            int j = c0 + jj;
            if (j < cnt) {
                float b = bas8[(size_t)(beg + j) * 8 + s];
                int k = kidb[(size_t)(beg + j) * 8 + s];
                Bt[k * BTSTRIDE + jj] = bf16_rne(b);
            }
        }
        int srcv[8];
#pragma unroll
        for (int j = 0; j < 8; ++j) {
            int jc = c0 + q * 8 + j;
            jc = (jc < cnt) ? jc : (cnt - 1);
            srcv[j] = srcs[beg + jc];
        }
        bf16x8 afr[3];
#pragma unroll
        for (int mt = 0; mt < 3; ++mt) {
            uint4 raw = *(const uint4*)&Bt[(mt * 16 + l15) * BTSTRIDE + q * 8];
            afr[mt] = __builtin_bit_cast(bf16x8, raw);
        }
#pragma unroll
        for (int nt = 0; nt < NT; ++nt) {
            unsigned int bw[4];
#pragma unroll
            for (int jp = 0; jp < 4; ++jp) {
                unsigned int lo = hbf[(size_t)srcv[2 * jp] * CIN + nt * 16 + l15];
                unsigned int hi = hbf[(size_t)srcv[2 * jp + 1] * CIN + nt * 16 + l15];
                bw[jp] = lo | (hi << 16);
            }
            uint4 braw = make_uint4(bw[0], bw[1], bw[2], bw[3]);
            bf16x8 bfr = __builtin_bit_cast(bf16x8, braw);
#pragma unroll
            for (int mt = 0; mt < 3; ++mt)
                acc[mt][nt] = __builtin_amdgcn_mfma_f32_16x16x32_bf16(afr[mt], bfr,
                                                                      acc[mt][nt], 0, 0, 0);
        }
    }

    unsigned short* arow = abuf + (size_t)n_local * (49 * CIN);
#pragma unroll
    for (int mt = 0; mt < 3; ++mt)
#pragma unroll
        for (int nt = 0; nt < NT; ++nt)
#pragma unroll
            for (int r = 0; r < 4; ++r) {
                int kk = mt * 16 + q * 4 + r;
                int ch = nt * 16 + l15;
                arow[kk * CIN + ch] = bf16_rne(acc[mt][nt][r]);
            }
    if (lane < CIN) arow[KTOT * CIN + lane] = hbf[(size_t)n * CIN + lane];
}

// ---------------------------------------------------------------------------
// Pack W' = [W(KK rows); root(CP rows)] into MFMA B-fragment order.
// ---------------------------------------------------------------------------
__global__ void pack_w_kernel(const float* __restrict__ W, const float* __restrict__ root,
                              int KK, int NN, int total, unsigned short* __restrict__ Wp) {
    int tid = blockIdx.x * 256 + threadIdx.x;
    if (tid >= total) return;
    int nct = NN >> 4;
    int l = tid & 63;
    int c = (tid >> 6) % nct;
    int t = tid / (64 * nct);
    int n = c * 16 + (l & 15);
    int kbase = t * 32 + ((l >> 4) << 3);
    unsigned short vals[8];
#pragma unroll
    for (int jj = 0; jj < 8; ++jj) {
        int k = kbase + jj;
        float v = (k < KK) ? W[(size_t)k * NN + n] : root[(size_t)(k - KK) * NN + n];
        vals[jj] = bf16_rne(v);
    }
    *(uint4*)&Wp[(size_t)tid * 8] = *(uint4*)vals;
}

// ---------------------------------------------------------------------------
// Layer-2 GEMM: block-internal K-split, zero atomics (R13 proven shape).
// h2 = bf16(relu(sum + bias)).
// ---------------------------------------------------------------------------
template <int NCT, int NW>
__global__ __launch_bounds__(NW * 64) void mfma_gemm_block(
    const unsigned short* __restrict__ A, const unsigned short* __restrict__ Wp,
    const float* __restrict__ bias, unsigned short* __restrict__ outb,
    int Kp, int n0, int mc) {
    constexpr int NN = NCT * 16;
    constexpr int RSTR = NN + 2;
    __shared__ float red[NW][16 * RSTR];
    int w = threadIdx.x >> 6, lane = threadIdx.x & 63;
    int q = lane >> 4, l15 = lane & 15;
    int row_local = blockIdx.x * 16 + l15;
    int row_c = min(row_local, mc - 1);
    const unsigned short* arow = A + (size_t)row_c * Kp + (q << 3);
    const uint4* wpq = (const uint4*)Wp;
    f32x4 acc[NCT] = {};
    int tsteps = Kp >> 5;
    int t0 = (w * tsteps) / NW;
    int t1 = ((w + 1) * tsteps) / NW;

    uint4 na = *(const uint4*)(arow + t0 * 32);
    uint4 nb[NCT];
    {
        const uint4* bb = wpq + ((size_t)t0 * NCT) * 64 + lane;
#pragma unroll
        for (int c = 0; c < NCT; ++c) nb[c] = bb[c * 64];
    }
    for (int t = t0; t < t1; ++t) {
        uint4 ca = na;
        uint4 cb[NCT];
#pragma unroll
        for (int c = 0; c < NCT; ++c) cb[c] = nb[c];
        int tn = (t + 1 < t1) ? t + 1 : t;
        na = *(const uint4*)(arow + tn * 32);
        const uint4* bb = wpq + ((size_t)tn * NCT) * 64 + lane;
#pragma unroll
        for (int c = 0; c < NCT; ++c) nb[c] = bb[c * 64];
        bf16x8 af = __builtin_bit_cast(bf16x8, ca);
#pragma unroll
        for (int c = 0; c < NCT; ++c) {
            bf16x8 bfr = __builtin_bit_cast(bf16x8, cb[c]);
            acc[c] = __builtin_amdgcn_mfma_f32_16x16x32_bf16(af, bfr, acc[c], 0, 0, 0);
        }
    }

    float* myred = &red[w][0];
#pragma unroll
    for (int c = 0; c < NCT; ++c)
#pragma unroll
        for (int r = 0; r < 4; ++r)
            myred[(q * 4 + r) * RSTR + c * 16 + l15] = acc[c][r];
    __syncthreads();

    for (int l = threadIdx.x; l < 16 * NN; l += NW * 64) {
        int row = l / NN, col = l % NN;
        int idx = row * RSTR + col;
        float v = 0.0f;
#pragma unroll
        for (int i = 0; i < NW; ++i) v += red[i][idx];
        v = fmaxf(v + bias[col], 0.0f);
        int ro = blockIdx.x * 16 + row;
        if (ro < mc) outb[(size_t)(n0 + ro) * NN + col] = bf16_rne(v);
    }
}

// ---------------------------------------------------------------------------
// FUSED layer 3: acc + GEMM + bias/relu/log_softmax in ONE kernel.
// Block = 512 threads (8 waves), 16 nodes (20000 = 1250 x 16 exactly).
// Phase 1: each wave accumulates 2 nodes (proven mfma_acc<64> body),
//          writes the bf16 A-row [acc(3072) | h2(64)] to LDS (padded rows).
// Phase 2: wave w owns column-tile w of the 16x128 output: 98 MFMAs with
//          A from LDS (ds_read_b128), B from L2-hot Wp3. No K-split, no
//          reduction. C staged to LDS overlay, fused log_softmax epilogue.
// No global intermediate at all for layer 3.
// ---------------------------------------------------------------------------
#define ASTR 3152   // ushorts per LDS A row (3136 + 16 pad; keeps ds_read_b128 bank-even)
__global__ __launch_bounds__(512) void fused_l3_kernel(
    const int* __restrict__ srcs, const float* __restrict__ bas8,
    const unsigned char* __restrict__ kidb, const int* __restrict__ row_start,
    const unsigned short* __restrict__ h2bf, const unsigned short* __restrict__ Wp3,
    const float* __restrict__ b3, float* __restrict__ out) {
    __shared__ unsigned short Arows[16 * ASTR];           // 100,864 B
    __shared__ unsigned short BtAll[8][KTOT * BTSTRIDE];  // 30,720 B (Cst overlay)
    float* Cst = (float*)&BtAll[0][0];                    // 16 x 130 fp32 (8.3 KB)
    int w = threadIdx.x >> 6, lane = threadIdx.x & 63;
    int q = lane >> 4, l15 = lane & 15;
    unsigned short* Bt = &BtAll[w][0];

    // ---- phase 1: accumulate, 2 nodes per wave ----
    for (int u = 0; u < 2; ++u) {
        int slot = w * 2 + u;
        int n = blockIdx.x * 16 + slot;
        int beg = row_start[n], end = row_start[n + 1];
        int cnt = end - beg;
        f32x4 acc[3][4] = {};
        for (int c0 = 0; c0 < cnt; c0 += 32) {
            uint4 z = make_uint4(0, 0, 0, 0);
            for (int l = lane; l < (KTOT * BTSTRIDE) / 8; l += 64) ((uint4*)Bt)[l] = z;
#pragma unroll
            for (int it = 0; it < 4; ++it) {
                int idx = it * 64 + lane;
                int jj = idx >> 3, s = idx & 7;
                int j = c0 + jj;
                if (j < cnt) {
                    float b = bas8[(size_t)(beg + j) * 8 + s];
                    int k = kidb[(size_t)(beg + j) * 8 + s];
                    Bt[k * BTSTRIDE + jj] = bf16_rne(b);
                }
            }
            int srcv[8];
#pragma unroll
            for (int j = 0; j < 8; ++j) {
                int jc = c0 + q * 8 + j;
                jc = (jc < cnt) ? jc : (cnt - 1);
                srcv[j] = srcs[beg + jc];
            }
            bf16x8 afr[3];
#pragma unroll
            for (int mt = 0; mt < 3; ++mt) {
                uint4 raw = *(const uint4*)&Bt[(mt * 16 + l15) * BTSTRIDE + q * 8];
                afr[mt] = __builtin_bit_cast(bf16x8, raw);
            }
#pragma unroll
            for (int nt = 0; nt < 4; ++nt) {
                unsigned int bw[4];
#pragma unroll
                for (int jp = 0; jp < 4; ++jp) {
                    unsigned int lo = h2bf[(size_t)srcv[2 * jp] * 64 + nt * 16 + l15];
                    unsigned int hi = h2bf[(size_t)srcv[2 * jp + 1] * 64 + nt * 16 + l15];
                    bw[jp] = lo | (hi << 16);
                }
                uint4 braw = make_uint4(bw[0], bw[1], bw[2], bw[3]);
                bf16x8 bfr = __builtin_bit_cast(bf16x8, braw);
#pragma unroll
                for (int mt = 0; mt < 3; ++mt)
                    acc[mt][nt] = __builtin_amdgcn_mfma_f32_16x16x32_bf16(
                        afr[mt], bfr, acc[mt][nt], 0, 0, 0);
            }
        }
        // writeout to LDS A row (same mapping as the proven abuf writeout)
        unsigned short* arow = &Arows[slot * ASTR];
#pragma unroll
        for (int mt = 0; mt < 3; ++mt)
#pragma unroll
            for (int nt = 0; nt < 4; ++nt)
#pragma unroll
                for (int r = 0; r < 4; ++r)
                    arow[(mt * 16 + q * 4 + r) * 64 + nt * 16 + l15] =
                        bf16_rne(acc[mt][nt][r]);
        arow[3072 + lane] = h2bf[(size_t)n * 64 + lane];
    }
    __syncthreads();

    // ---- phase 2: wave w = column tile w; full K from LDS ----
    f32x4 cacc = {};
    const uint4* wpq = (const uint4*)Wp3;
    uint4 nb = wpq[(size_t)w * 64 + lane];
    for (int t = 0; t < 98; ++t) {
        uint4 cb = nb;
        int tn = (t + 1 < 98) ? t + 1 : t;
        nb = wpq[((size_t)tn * 8 + w) * 64 + lane];
        bf16x8 af = __builtin_bit_cast(
            bf16x8, *(const uint4*)&Arows[l15 * ASTR + t * 32 + (q << 3)]);
        bf16x8 bfr = __builtin_bit_cast(bf16x8, cb);
        cacc = __builtin_amdgcn_mfma_f32_16x16x32_bf16(af, bfr, cacc, 0, 0, 0);
    }
    // stage C (Bt region is dead after phase 1; all phase-1 done at the barrier)
#pragma unroll
    for (int r = 0; r < 4; ++r)
        Cst[(q * 4 + r) * 130 + w * 16 + l15] = cacc[r];
    __syncthreads();

    // ---- fused epilogue: bias + relu + log_softmax, 16 threads/row ----
    if (threadIdx.x < 256) {
        int row = threadIdx.x >> 4;
        int cb0 = threadIdx.x & 15;
        float v[8];
        float mx = -1e30f;
#pragma unroll
        for (int c = 0; c < 8; ++c) {
            float s = Cst[row * 130 + cb0 + c * 16] + b3[cb0 + c * 16];
            s = fmaxf(s, 0.0f);
            v[c] = s;
            mx = fmaxf(mx, s);
        }
#pragma unroll
        for (int off = 8; off > 0; off >>= 1) mx = fmaxf(mx, __shfl_xor(mx, off));
        float se = 0.0f;
#pragma unroll
        for (int c = 0; c < 8; ++c) se += expf(v[c] - mx);
#pragma unroll
        for (int off = 8; off > 0; off >>= 1) se += __shfl_xor(se, off);
        float lse = mx + logf(se);
        int n = blockIdx.x * 16 + row;
#pragma unroll
        for (int c = 0; c < 8; ++c)
            out[(size_t)n * 128 + cb0 + c * 16] = v[c] - lse;
    }
}

// ---------------------------------------------------------------------------
// Launch
// ---------------------------------------------------------------------------
extern "C" void kernel_launch(void* const* d_in, const int* in_sizes, int n_in,
                              void* d_out, int out_size, void* d_ws, size_t ws_size,
                              hipStream_t stream) {
    const float* x = (const float*)d_in[0];
    const int* ei = (const int*)d_in[1];
    const float* pseudo = (const float*)d_in[2];
    const float* W1 = (const float*)d_in[3];
    const float* root1 = (const float*)d_in[4];
    const float* b1 = (const float*)d_in[5];
    const float* W2 = (const float*)d_in[6];
    const float* root2 = (const float*)d_in[7];
    const float* b2 = (const float*)d_in[8];
    const float* W3 = (const float*)d_in[9];
    const float* root3 = (const float*)d_in[10];
    const float* b3 = (const float*)d_in[11];
    float* out = (float*)d_out;
    char* ws = (char*)d_ws;

    const int N = NN_NODES, E = NE_EDGES;
    const int Kp2 = 49 * 32;   // 1568
    const int Kp3 = 49 * 64;   // 3136
    size_t off = 0;
    auto carve = [&](size_t bytes) {
        size_t p = off;
        off += (bytes + 255) & ~(size_t)255;
        return p;
    };
    int* counts = (int*)(ws + carve((size_t)N * 4 * 2));
    int* cursor = counts + N;
    int* row_start = (int*)(ws + carve((size_t)(N + 1) * 4));
    int* slot_pos = (int*)(ws + carve((size_t)E * 4));
    int* srcs = (int*)(ws + carve((size_t)E * 4));
    float* bas8 = (float*)(ws + carve((size_t)E * 8 * 4));
    unsigned char* kidb = (unsigned char*)(ws + carve((size_t)E * 8));
    unsigned short* h1bf = (unsigned short*)(ws + carve((size_t)N * 32 * 2));
    unsigned short* h2bf = (unsigned short*)(ws + carve((size_t)N * 64 * 2));
    unsigned short* Wp2 = (unsigned short*)(ws + carve((size_t)Kp2 * 64 * 2));
    unsigned short* Wp3 = (unsigned short*)(ws + carve((size_t)Kp3 * 128 * 2));
    size_t rem = (ws_size > off) ? (ws_size - off) : 0;
    unsigned short* abuf = (unsigned short*)(ws + off);

    int ch2 = (int)(rem / ((size_t)Kp2 * 2));
    if (ch2 > N) ch2 = N;
    if (ch2 < 1) ch2 = 1;

    int egrid = (E + 255) / 256;

    // CSR + sorted edge metadata
    zero_kernel<<<(2 * N + 255) / 256, 256, 0, stream>>>(counts, 2 * N);
    count_kernel<<<egrid, 256, 0, stream>>>(ei, counts);
    scan_kernel<<<1, 256, 0, stream>>>(counts, row_start);
    fill_kernel<<<egrid, 256, 0, stream>>>(ei, row_start, cursor, slot_pos);
    edge_prep_sorted<<<egrid, 256, 0, stream>>>(pseudo, ei, slot_pos, srcs, bas8, kidb);

    // pack weights (bf16 MFMA B-fragment order)
    int tot2 = (Kp2 / 32) * (64 / 16) * 64;
    int tot3 = (Kp3 / 32) * (128 / 16) * 64;
    pack_w_kernel<<<(tot2 + 255) / 256, 256, 0, stream>>>(W2, root2, KTOT * 32, 64, tot2, Wp2);
    pack_w_kernel<<<(tot3 + 255) / 256, 256, 0, stream>>>(W3, root3, KTOT * 64, 128, tot3, Wp3);

    // layer 1 (fused accumulate + dense + relu) -> bf16 h1
    layer1_fused_kernel<<<(N + 3) / 4, 256, 0, stream>>>(srcs, bas8, kidb, row_start, x,
                                                         W1, root1, b1, h1bf);

    // layer 2 (MFMA accumulate -> block-K-split GEMM) -> bf16 h2
    for (int n0 = 0; n0 < N; n0 += ch2) {
        int mc = N - n0 < ch2 ? N - n0 : ch2;
        mfma_acc_kernel<32><<<(mc + 3) / 4, 256, 0, stream>>>(
            srcs, bas8, kidb, row_start, h1bf, abuf, n0, mc);
        mfma_gemm_block<4, 4><<<(mc + 15) / 16, 256, 0, stream>>>(
            abuf, Wp2, b2, h2bf, Kp2, n0, mc);
    }

    // layer 3: single fused kernel (acc + GEMM + bias/relu/log_softmax)
    fused_l3_kernel<<<N / 16, 512, 0, stream>>>(srcs, bas8, kidb, row_start,
                                                h2bf, Wp3, b3, out);
}